// Round 2
// baseline (6091.960 us; speedup 1.0000x reference)
//
#include <hip/hip_runtime.h>
#include <hip/hip_bf16.h>
#include <math.h>

#define B 4096
#define D 1024
#define F 24576
#define TOPK 32
#define DEAD_TOPK 256
#define DEAD_CUTOFF 100000

#define NCMAX1 64     // candidate cap for top-32   (32 + 16 pad, rounded up)
#define NCMAX2 288    // candidate cap for top-256  (256 + 16 pad + tie slack)
#define PAD_K 16

// ---------- helpers ----------
__device__ __forceinline__ unsigned toOrd(float x) {
    unsigned u = __float_as_uint(x);
    return (u & 0x80000000u) ? ~u : (u | 0x80000000u);
}

// ---------- Kernel 1: project = (embed - bias) @ W^T, fused sum/sumsq ----------
#define BM 64
#define BN 64
#define BK 32

__global__ __launch_bounds__(256) void gemm_proj(
    const float* __restrict__ embed, const float* __restrict__ bias,
    const float* __restrict__ W, float* __restrict__ proj,
    double* __restrict__ stats)
{
    __shared__ float As[BK][BM + 4];
    __shared__ float Ws[BK][BN + 4];
    __shared__ float rs[256], rq[256];

    const int row0 = blockIdx.y * BM;
    const int col0 = blockIdx.x * BN;
    const int tid  = threadIdx.x;
    const int trow = tid >> 4;
    const int tcol = tid & 15;

    float acc[4][4] = {};

    for (int k0 = 0; k0 < D; k0 += BK) {
        #pragma unroll
        for (int it = 0; it < 2; ++it) {
            int idx = it * 256 + tid;
            int m  = idx >> 3;
            int kq = idx & 7;
            float4 a  = *(const float4*)&embed[(size_t)(row0 + m) * D + k0 + kq * 4];
            float4 bv = *(const float4*)&bias[k0 + kq * 4];
            As[kq * 4 + 0][m] = a.x - bv.x;
            As[kq * 4 + 1][m] = a.y - bv.y;
            As[kq * 4 + 2][m] = a.z - bv.z;
            As[kq * 4 + 3][m] = a.w - bv.w;
            float4 w = *(const float4*)&W[(size_t)(col0 + m) * D + k0 + kq * 4];
            Ws[kq * 4 + 0][m] = w.x;
            Ws[kq * 4 + 1][m] = w.y;
            Ws[kq * 4 + 2][m] = w.z;
            Ws[kq * 4 + 3][m] = w.w;
        }
        __syncthreads();
        #pragma unroll
        for (int kk = 0; kk < BK; ++kk) {
            float a[4], w[4];
            *(float4*)a = *(const float4*)&As[kk][trow * 4];
            *(float4*)w = *(const float4*)&Ws[kk][tcol * 4];
            #pragma unroll
            for (int i = 0; i < 4; ++i)
                #pragma unroll
                for (int j = 0; j < 4; ++j)
                    acc[i][j] = fmaf(a[i], w[j], acc[i][j]);
        }
        __syncthreads();
    }

    float s = 0.f, sq = 0.f;
    #pragma unroll
    for (int i = 0; i < 4; ++i) {
        float4 c;
        c.x = acc[i][0]; c.y = acc[i][1]; c.z = acc[i][2]; c.w = acc[i][3];
        *(float4*)&proj[(size_t)(row0 + trow * 4 + i) * F + col0 + tcol * 4] = c;
        s  += c.x + c.y + c.z + c.w;
        sq += c.x * c.x + c.y * c.y + c.z * c.z + c.w * c.w;
    }
    rs[tid] = s; rq[tid] = sq;
    __syncthreads();
    for (int off = 128; off > 0; off >>= 1) {
        if (tid < off) { rs[tid] += rs[tid + off]; rq[tid] += rq[tid + off]; }
        __syncthreads();
    }
    if (tid == 0) {
        atomicAdd(&stats[0], (double)rs[0]);
        atomicAdd(&stats[1], (double)rq[0]);
    }
}

// ---------- Kernel 2: finalize std ----------
__global__ void finalize_std(const double* __restrict__ stats, double* __restrict__ sd)
{
    double n   = (double)B * (double)F;
    double var = (stats[1] - stats[0] * stats[0] / n) / (n - 1.0);
    sd[0] = sqrt(var);
}

// ---------- Kernel 3: per-row top-32 (fp64-refined) + embed_recon ----------
__global__ __launch_bounds__(256) void topk_recon(
    const float* __restrict__ proj, const float* __restrict__ lookup,
    const float* __restrict__ bias, const float* __restrict__ embed,
    const float* __restrict__ W, float* __restrict__ out)
{
    const int b    = blockIdx.x;
    const int tid  = threadIdx.x;
    const int lane = tid & 63;
    const int wid  = tid >> 6;
    const float* prow = proj + (size_t)b * F;

    __shared__ double   eb[D];                 // (embed - bias) in fp64
    __shared__ unsigned hist[256];
    __shared__ unsigned sh_prefix;
    __shared__ int      sh_k;
    __shared__ int      candF[NCMAX1];
    __shared__ double   candKey[NCMAX1];
    __shared__ int      candN;
    __shared__ int      selF[TOPK];
    __shared__ float    selW[TOPK];

    for (int d = tid; d < D; d += 256)
        eb[d] = (double)embed[(size_t)b * D + d] - (double)bias[d];
    if (tid == 0) candN = 0;

    // -- radix select threshold for top-(TOPK+PAD_K) on fp32 ordinals --
    unsigned prefix = 0;
    int k = TOPK + PAD_K;
    for (int pass = 0; pass < 4; ++pass) {
        hist[tid] = 0;
        __syncthreads();
        int shift = 24 - 8 * pass;
        for (int f = tid; f < F; f += 256) {
            unsigned key = toOrd(prow[f]);
            if (pass == 0 || (key >> (32 - 8 * pass)) == prefix)
                atomicAdd(&hist[(key >> shift) & 255u], 1u);
        }
        __syncthreads();
        if (tid == 0) {
            int cum = 0, bsel = 0;
            for (int bin = 255; bin >= 0; --bin) {
                cum += (int)hist[bin];
                if (cum >= k) { bsel = bin; k -= (cum - (int)hist[bin]); break; }
            }
            sh_prefix = (prefix << 8) | (unsigned)bsel;
            sh_k = k;
        }
        __syncthreads();
        prefix = sh_prefix;
        k = sh_k;
        __syncthreads();
    }
    const unsigned T = prefix;

    // -- collect candidate superset: all keys >= T --
    for (int f = tid; f < F; f += 256) {
        if (toOrd(prow[f]) >= T) {
            int p = atomicAdd(&candN, 1);
            if (p < NCMAX1) candF[p] = f;
        }
    }
    __syncthreads();
    const int nc = candN < NCMAX1 ? candN : NCMAX1;

    // -- fp64 refinement: exact project value per candidate (one wave per cand) --
    for (int c0 = 0; c0 < nc; c0 += 4) {
        int c = c0 + wid;
        double acc = 0.0;
        if (c < nc) {
            const float* wr = W + (size_t)candF[c] * D;
            #pragma unroll
            for (int i = 0; i < 16; ++i) {
                int d = i * 64 + lane;
                acc += eb[d] * (double)wr[d];
            }
        }
        #pragma unroll
        for (int off = 32; off > 0; off >>= 1)
            acc += __shfl_down(acc, off, 64);
        if (c < nc && lane == 0) candKey[c] = acc;
    }
    __syncthreads();

    // -- exact ranking (n^2, parallel) --
    for (int i = tid; i < nc; i += 256) {
        double ki = candKey[i];
        int    fi = candF[i];
        int r = 0;
        for (int j = 0; j < nc; ++j) {
            double kj = candKey[j];
            if (kj > ki || (kj == ki && candF[j] < fi)) ++r;
        }
        if (r < TOPK) { selF[r] = fi; selW[r] = (float)ki; }
    }
    __syncthreads();

    // -- weighted gather-sum + bias --
    const int col = tid * 4;
    float ax = 0.f, ay = 0.f, az = 0.f, aw = 0.f;
    #pragma unroll 4
    for (int i = 0; i < TOPK; ++i) {
        float w = selW[i];
        const float4 v = *(const float4*)&lookup[(size_t)selF[i] * D + col];
        ax = fmaf(w, v.x, ax); ay = fmaf(w, v.y, ay);
        az = fmaf(w, v.z, az); aw = fmaf(w, v.w, aw);
    }
    float4 bv = *(const float4*)&bias[col];
    float4 o; o.x = ax + bv.x; o.y = ay + bv.y; o.z = az + bv.z; o.w = aw + bv.w;
    *(float4*)&out[(size_t)b * D + col] = o;
}

// ---------- Kernel 4: per-row dead top-256 (fp64-refined) + undead_recon ----------
__global__ __launch_bounds__(256) void dead_topk_recon(
    const float* __restrict__ proj, const float* __restrict__ noise,
    const int* __restrict__ last_usage, const float* __restrict__ lookup,
    const double* __restrict__ sdp, const float* __restrict__ embed,
    const float* __restrict__ bias, const float* __restrict__ W,
    float* __restrict__ out)
{
    const int b    = blockIdx.x;
    const int tid  = threadIdx.x;
    const int lane = tid & 63;
    const int wid  = tid >> 6;
    const float* prow = proj  + (size_t)b * F;
    const float* nrow = noise + (size_t)b * F;
    const double sd64 = sdp[0];
    const float  sd   = (float)sd64;

    __shared__ double   eb[D];
    __shared__ unsigned hist[256];
    __shared__ unsigned sh_prefix;
    __shared__ int      sh_k;
    __shared__ int      candF[NCMAX2];
    __shared__ double   candKey[NCMAX2];   // fuzzed key (p64 + sd*n)
    __shared__ float    candW[NCMAX2];     // refined project weight
    __shared__ int      candN;
    __shared__ int      selF[DEAD_TOPK];
    __shared__ float    selW[DEAD_TOPK];

    for (int d = tid; d < D; d += 256)
        eb[d] = (double)embed[(size_t)b * D + d] - (double)bias[d];
    if (tid == 0) candN = 0;

    // -- radix select threshold for top-(DEAD_TOPK+PAD_K) on fp32 fuzzed ordinals --
    unsigned prefix = 0;
    int k = DEAD_TOPK + PAD_K;
    for (int pass = 0; pass < 4; ++pass) {
        hist[tid] = 0;
        __syncthreads();
        int shift = 24 - 8 * pass;
        for (int f = tid; f < F; f += 256) {
            unsigned key = 0;
            if (last_usage[f] > DEAD_CUTOFF)
                key = toOrd(__fadd_rn(prow[f], __fmul_rn(sd, nrow[f])));
            if (key != 0 && (pass == 0 || (key >> (32 - 8 * pass)) == prefix))
                atomicAdd(&hist[(key >> shift) & 255u], 1u);
        }
        __syncthreads();
        if (tid == 0) {
            int cum = 0, bsel = 0;
            for (int bin = 255; bin >= 0; --bin) {
                cum += (int)hist[bin];
                if (cum >= k) { bsel = bin; k -= (cum - (int)hist[bin]); break; }
            }
            sh_prefix = (prefix << 8) | (unsigned)bsel;
            sh_k = k;
        }
        __syncthreads();
        prefix = sh_prefix;
        k = sh_k;
        __syncthreads();
    }
    const unsigned T = prefix;

    // -- collect candidate superset: dead features with key >= T --
    for (int f = tid; f < F; f += 256) {
        if (last_usage[f] > DEAD_CUTOFF) {
            unsigned key = toOrd(__fadd_rn(prow[f], __fmul_rn(sd, nrow[f])));
            if (key >= T) {
                int p = atomicAdd(&candN, 1);
                if (p < NCMAX2) candF[p] = f;
            }
        }
    }
    __syncthreads();
    const int nc = candN < NCMAX2 ? candN : NCMAX2;

    // -- fp64 refinement (one wave per candidate) --
    for (int c0 = 0; c0 < nc; c0 += 4) {
        int c = c0 + wid;
        double acc = 0.0;
        int f = 0;
        if (c < nc) {
            f = candF[c];
            const float* wr = W + (size_t)f * D;
            #pragma unroll
            for (int i = 0; i < 16; ++i) {
                int d = i * 64 + lane;
                acc += eb[d] * (double)wr[d];
            }
        }
        #pragma unroll
        for (int off = 32; off > 0; off >>= 1)
            acc += __shfl_down(acc, off, 64);
        if (c < nc && lane == 0) {
            candW[c]   = (float)acc;                       // un-fuzzed weight
            candKey[c] = acc + sd64 * (double)nrow[f];     // exact fuzzed key
        }
    }
    __syncthreads();

    // -- exact ranking --
    for (int i = tid; i < nc; i += 256) {
        double ki = candKey[i];
        int    fi = candF[i];
        int r = 0;
        for (int j = 0; j < nc; ++j) {
            double kj = candKey[j];
            if (kj > ki || (kj == ki && candF[j] < fi)) ++r;
        }
        if (r < DEAD_TOPK) { selF[r] = fi; selW[r] = candW[i]; }
    }
    __syncthreads();

    // -- weighted gather-sum (no bias) --
    const int col = tid * 4;
    float ax = 0.f, ay = 0.f, az = 0.f, aw = 0.f;
    #pragma unroll 4
    for (int i = 0; i < DEAD_TOPK; ++i) {
        float w = selW[i];
        const float4 v = *(const float4*)&lookup[(size_t)selF[i] * D + col];
        ax = fmaf(w, v.x, ax); ay = fmaf(w, v.y, ay);
        az = fmaf(w, v.z, az); aw = fmaf(w, v.w, aw);
    }
    float4 o; o.x = ax; o.y = ay; o.z = az; o.w = aw;
    *(float4*)&out[(size_t)b * D + col] = o;
}

// ---------- launch ----------
extern "C" void kernel_launch(void* const* d_in, const int* in_sizes, int n_in,
                              void* d_out, int out_size, void* d_ws, size_t ws_size,
                              hipStream_t stream)
{
    const float* embed      = (const float*)d_in[0];
    const float* enc_bias   = (const float*)d_in[1];
    const float* enc_W      = (const float*)d_in[2];
    const float* lookup     = (const float*)d_in[3];
    const float* noise      = (const float*)d_in[4];
    const int*   last_usage = (const int*)d_in[5];
    float* out = (float*)d_out;

    char* ws = (char*)d_ws;
    const size_t projBytes = (size_t)B * F * sizeof(float);
    float*  proj  = (float*)ws;
    double* stats = (double*)(ws + projBytes);
    double* sdp   = (double*)(ws + projBytes + 2 * sizeof(double));

    hipMemsetAsync(stats, 0, 2 * sizeof(double), stream);

    gemm_proj<<<dim3(F / BN, B / BM), 256, 0, stream>>>(embed, enc_bias, enc_W, proj, stats);
    finalize_std<<<1, 1, 0, stream>>>(stats, sdp);
    topk_recon<<<B, 256, 0, stream>>>(proj, lookup, enc_bias, embed, enc_W, out);
    dead_topk_recon<<<B, 256, 0, stream>>>(proj, noise, last_usage, lookup, sdp,
                                           embed, enc_bias, enc_W,
                                           out + (size_t)B * D);
}